// Round 6
// baseline (374.396 us; speedup 1.0000x reference)
//
#include <hip/hip_runtime.h>
#include <hip/hip_fp16.h>

#define CIN   64
#define COUT  64

typedef __attribute__((ext_vector_type(8))) short    bf16x8;
typedef __attribute__((ext_vector_type(4))) float    f32x4;
typedef __attribute__((ext_vector_type(2))) _Float16 f16x2;

#if __has_builtin(__builtin_amdgcn_global_atomic_fadd_v2f16)
#define HAVE_PK16 1
#else
#define HAVE_PK16 0
#endif

// round-to-nearest-even f32 -> bf16 (bit pattern as ushort)
__device__ inline unsigned short f2bf(float f) {
    unsigned u = __float_as_uint(f);
    return (unsigned short)((u + 0x7FFFu + ((u >> 16) & 1u)) >> 16);
}

// ---------------------------------------------------------------------------
// feats fp32 -> bf16 rows (one-time per launch; 51.2 MB read / 25.6 MB write)
// ---------------------------------------------------------------------------
__global__ __launch_bounds__(256)
void cvt_feats(const float4* __restrict__ in, unsigned short* __restrict__ outb,
               int n8) {
    int i = blockIdx.x * 256 + threadIdx.x;
    if (i >= n8) return;
    float4 f0 = in[2 * i], f1 = in[2 * i + 1];
    bf16x8 o;
    o[0] = (short)f2bf(f0.x); o[1] = (short)f2bf(f0.y);
    o[2] = (short)f2bf(f0.z); o[3] = (short)f2bf(f0.w);
    o[4] = (short)f2bf(f1.x); o[5] = (short)f2bf(f1.y);
    o[6] = (short)f2bf(f1.z); o[7] = (short)f2bf(f1.w);
    *(bf16x8*)(outb + 8 * (size_t)i) = o;
}

// ---------------------------------------------------------------------------
// fp16 accumulator -> fp32 out (every element written; no out-memset needed)
// ---------------------------------------------------------------------------
__global__ __launch_bounds__(256)
void cvt_out(const __half2* __restrict__ hacc, float2* __restrict__ out, int n2) {
    int i = blockIdx.x * 256 + threadIdx.x;   // i indexes half2 / float2 pairs
    if (i >= n2) return;
    const __half2 h = hacc[i];
    out[i] = make_float2(__half2float(__low2half(h)), __half2float(__high2half(h)));
}

#if HAVE_PK16
// ---------------------------------------------------------------------------
// Single-phase implicit-GEMM with packed-fp16 atomic scatter.
// One wave = 16 pairs/iter via v_mfma_f32_16x16x32_bf16; W[k] in registers;
// A gathered from pre-converted bf16 feats (2x16B loads/lane, no cvt).
// Scatter: cols paired via shfl_xor(1) -> ONE global_atomic_pk_add_f16 per
// 2 cols (4B sub-op at TCC; halves atomic-op count vs scalar f32).
// ---------------------------------------------------------------------------
__global__ __launch_bounds__(256)
void spconv_pk(const unsigned short* __restrict__ featsb,
               const float*          __restrict__ weight,
               const int*            __restrict__ in_map,
               const int*            __restrict__ out_map,
               __half*               __restrict__ hacc,
               int M) {
    const int k      = blockIdx.y;
    const int tid    = threadIdx.x;
    const int lane   = tid & 63;
    const int m      = lane & 15;
    const int quad   = lane >> 4;
    const int wave   = blockIdx.x * 4 + (tid >> 6);
    const int nwaves = gridDim.x * 4;
    const bool odd   = (m & 1);

    // Preload B fragments: b[t][h][j] = W[k][32h+8q+j][16t+m]
    const float* __restrict__ wk = weight + (size_t)k * (CIN * COUT);
    bf16x8 bfrag[4][2];
#pragma unroll
    for (int t = 0; t < 4; ++t)
#pragma unroll
        for (int h = 0; h < 2; ++h) {
            const int n  = 16 * t + m;
            const int c0 = 32 * h + 8 * quad;
#pragma unroll
            for (int j = 0; j < 8; ++j)
                bfrag[t][h][j] = (short)f2bf(wk[(c0 + j) * COUT + n]);
        }

    const int base   = k * M;
    const int ntiles = M >> 4;   // 3125

    typedef __attribute__((address_space(1))) f16x2 gf16x2;
    f16x2* const hacc2 = (f16x2*)hacc;

    for (int tile = wave; tile < ntiles; tile += nwaves) {
        const int p0      = tile << 4;
        const int in_row  = in_map[base + p0 + m];
        const int out_row = out_map[base + p0 + m];

        const unsigned short* fb = featsb + ((size_t)in_row << 6) + 8 * quad;
        const bf16x8 a0 = *(const bf16x8*)fb;          // channels [8q, 8q+8)
        const bf16x8 a1 = *(const bf16x8*)(fb + 32);   // channels [8q+32, 8q+40)

        // out rows for this lane's C rows (4q + r)
        int orow[4];
#pragma unroll
        for (int r = 0; r < 4; ++r)
            orow[r] = __shfl(out_row, 4 * quad + r);

        f32x4 acc[4];
#pragma unroll
        for (int t = 0; t < 4; ++t) {
            acc[t] = {0.f, 0.f, 0.f, 0.f};
            acc[t] = __builtin_amdgcn_mfma_f32_16x16x32_bf16(a0, bfrag[t][0], acc[t], 0, 0, 0);
            acc[t] = __builtin_amdgcn_mfma_f32_16x16x32_bf16(a1, bfrag[t][1], acc[t], 0, 0, 0);
        }

        // Pair cols (m, m^1) via shfl_xor(1): even lane takes C-rows 4q+{0,1},
        // odd lane rows 4q+{2,3}; one pk_add_f16 per (row, colpair).
        const int coldw = m >> 1;   // + 8t per tile below
        const int ra = odd ? orow[2] : orow[0];
        const int rb = odd ? orow[3] : orow[1];
#pragma unroll
        for (int t = 0; t < 4; ++t) {
            const float send0 = odd ? acc[t][0] : acc[t][2];
            const float send1 = odd ? acc[t][1] : acc[t][3];
            const float recv0 = __shfl_xor(send0, 1);
            const float recv1 = __shfl_xor(send1, 1);

            f16x2 va, vb;
            va[0] = (_Float16)(odd ? recv0 : acc[t][0]);
            va[1] = (_Float16)(odd ? acc[t][2] : recv0);
            vb[0] = (_Float16)(odd ? recv1 : acc[t][1]);
            vb[1] = (_Float16)(odd ? acc[t][3] : recv1);

            __builtin_amdgcn_global_atomic_fadd_v2f16(
                (gf16x2*)(unsigned long long)(void*)&hacc2[(size_t)ra * 32 + coldw + 8 * t], va);
            __builtin_amdgcn_global_atomic_fadd_v2f16(
                (gf16x2*)(unsigned long long)(void*)&hacc2[(size_t)rb * 32 + coldw + 8 * t], vb);
        }
    }
}
#endif  // HAVE_PK16

// ---------------------------------------------------------------------------
// Fallback: round-2 kernel — scalar f32 atomic scatter into out (known-good).
// ---------------------------------------------------------------------------
__global__ __launch_bounds__(256)
void spconv_atomic(const float* __restrict__ feats,
                   const float* __restrict__ weight,
                   const int*   __restrict__ in_map,
                   const int*   __restrict__ out_map,
                   float*       __restrict__ out,
                   int M) {
    const int k      = blockIdx.y;
    const int tid    = threadIdx.x;
    const int lane   = tid & 63;
    const int m      = lane & 15;
    const int quad   = lane >> 4;
    const int wave   = blockIdx.x * 4 + (tid >> 6);
    const int nwaves = gridDim.x * 4;

    const float* __restrict__ wk = weight + (size_t)k * (CIN * COUT);
    bf16x8 bfrag[4][2];
#pragma unroll
    for (int t = 0; t < 4; ++t)
#pragma unroll
        for (int h = 0; h < 2; ++h) {
            const int n  = 16 * t + m;
            const int c0 = 32 * h + 8 * quad;
#pragma unroll
            for (int j = 0; j < 8; ++j)
                bfrag[t][h][j] = (short)f2bf(wk[(c0 + j) * COUT + n]);
        }

    const int base   = k * M;
    const int ntiles = M >> 4;

    for (int tile = wave; tile < ntiles; tile += nwaves) {
        const int p0 = tile << 4;
        const int in_row  = in_map[base + p0 + m];
        const int out_row = out_map[base + p0 + m];

        const float* __restrict__ fr = feats + ((size_t)in_row << 6) + 8 * quad;
        const f32x4 f0 = *(const f32x4*)(fr + 0);
        const f32x4 f1 = *(const f32x4*)(fr + 4);
        const f32x4 f2 = *(const f32x4*)(fr + 32);
        const f32x4 f3 = *(const f32x4*)(fr + 36);

        bf16x8 a0, a1;
#pragma unroll
        for (int j = 0; j < 4; ++j) {
            a0[j]     = (short)f2bf(f0[j]);
            a0[j + 4] = (short)f2bf(f1[j]);
            a1[j]     = (short)f2bf(f2[j]);
            a1[j + 4] = (short)f2bf(f3[j]);
        }

        int orow[4];
#pragma unroll
        for (int r = 0; r < 4; ++r)
            orow[r] = __shfl(out_row, 4 * quad + r);

        f32x4 acc[4];
#pragma unroll
        for (int t = 0; t < 4; ++t) {
            acc[t] = {0.f, 0.f, 0.f, 0.f};
            acc[t] = __builtin_amdgcn_mfma_f32_16x16x32_bf16(a0, bfrag[t][0], acc[t], 0, 0, 0);
            acc[t] = __builtin_amdgcn_mfma_f32_16x16x32_bf16(a1, bfrag[t][1], acc[t], 0, 0, 0);
        }

#pragma unroll
        for (int t = 0; t < 4; ++t)
#pragma unroll
            for (int r = 0; r < 4; ++r)
                atomicAdd(out + (size_t)orow[r] * COUT + 16 * t + m, acc[t][r]);
    }
}

__global__ __launch_bounds__(256)
void zero_out_kernel(float4* __restrict__ out, int n4) {
    int i = blockIdx.x * 256 + threadIdx.x;
    if (i < n4) out[i] = make_float4(0.f, 0.f, 0.f, 0.f);
}

extern "C" void kernel_launch(void* const* d_in, const int* in_sizes, int n_in,
                              void* d_out, int out_size, void* d_ws, size_t ws_size,
                              hipStream_t stream) {
    const float* feats   = (const float*)d_in[0];
    const float* weight  = (const float*)d_in[1];
    const int*   in_map  = (const int*)d_in[2];
    const int*   out_map = (const int*)d_in[3];
    float*       out     = (float*)d_out;

    const int K = in_sizes[1] / (CIN * COUT);   // 27
    const int M = in_sizes[2] / K;              // 50000
    const int N = out_size / COUT;              // 200000

    // ws layout: featsb bf16[N*CIN] | hacc fp16[N*COUT]
    const size_t fb_b   = ((size_t)N * CIN * 2 + 255) & ~(size_t)255;
    const size_t hacc_b = (size_t)N * COUT * 2;
    const size_t need   = fb_b + hacc_b;

#if HAVE_PK16
    if ((M & 15) == 0 && ws_size >= need) {
        unsigned short* featsb = (unsigned short*)d_ws;
        __half*         hacc   = (__half*)((char*)d_ws + fb_b);

        hipMemsetAsync(hacc, 0, hacc_b, stream);          // fp16 0.0 == 0x0000

        const int n8 = N * CIN / 8;
        cvt_feats<<<(n8 + 255) / 256, 256, 0, stream>>>(
            (const float4*)feats, featsb, n8);

        dim3 grid(80, K);
        spconv_pk<<<grid, 256, 0, stream>>>(featsb, weight, in_map, out_map,
                                            hacc, M);

        const int n2 = N * COUT / 2;
        cvt_out<<<(n2 + 255) / 256, 256, 0, stream>>>(
            (const __half2*)hacc, (float2*)out, n2);
        return;
    }
#endif
    // Fallback: known-good scalar-atomic path.
    int n4 = out_size / 4;
    zero_out_kernel<<<(n4 + 255) / 256, 256, 0, stream>>>((float4*)out, n4);
    dim3 grid(80, K);
    spconv_atomic<<<grid, 256, 0, stream>>>(feats, weight, in_map, out_map, out, M);
}